// Round 1
// baseline (5593.241 us; speedup 1.0000x reference)
//
#include <hip/hip_runtime.h>

#define NBATCH 32
#define NDIM 512

// One wave (64 lanes) per batch element. Lane k owns columns [8k, 8k+8).
// Per row: parallel prep (sigmoid, fut, wave reverse-scan for mfm), then
// lane 0 runs the serial column recurrence on u = 1 - row_sum with a
// 3-op dependent chain per column, reading packed float4 constants from
// LDS (double-buffered 16-column chunks). Exact-ish early exit when
// u < 1e-12 and all remaining w >= 0 (tail p's are then < 1e-12).
__global__ __launch_bounds__(64, 1)
void sb_kernel(const float* __restrict__ x, const float* __restrict__ xm,
               float* __restrict__ out) {
  const int lane = threadIdx.x;
  const size_t base = (size_t)blockIdx.x * NDIM * NDIM;
  const float* xb = x + base;
  const float* mb = xm + base;
  float* ob = out + base;

  // padded: column n lives at n + (n>>3)  (one float4 pad per 8 columns
  // breaks the 128B-stride bank pattern on the 8 ds_write_b128 per lane)
  __shared__ float4 cons[NDIM + (NDIM >> 3)];
  __shared__ float pbuf[NDIM];

  float cs[8];
#pragma unroll
  for (int k = 0; k < 8; ++k) cs[k] = 0.0f;

  // prefetch row 0
  float4 xA = *(const float4*)(xb + lane * 8);
  float4 xB = *(const float4*)(xb + lane * 8 + 4);
  float4 mA = *(const float4*)(mb + lane * 8);
  float4 mB = *(const float4*)(mb + lane * 8 + 4);

#pragma unroll 1
  for (int m = 0; m < NDIM; ++m) {
    float xr[8] = {xA.x, xA.y, xA.z, xA.w, xB.x, xB.y, xB.z, xB.w};
    float mr[8] = {mA.x, mA.y, mA.z, mA.w, mB.x, mB.y, mB.z, mB.w};
    // issue next row's loads now; they complete during the serial scan
    if (m + 1 < NDIM) {
      const float* xn = xb + (size_t)(m + 1) * NDIM + lane * 8;
      const float* mn = mb + (size_t)(m + 1) * NDIM + lane * 8;
      xA = *(const float4*)(xn);
      xB = *(const float4*)(xn + 4);
      mA = *(const float4*)(mn);
      mB = *(const float4*)(mn + 4);
    }

    float w[8], fut[8], c1[8], c2[8];
    float S = 0.0f, wmn = 3.0e38f;
#pragma unroll
    for (int k = 0; k < 8; ++k) {
      float bb = 1.0f / (1.0f + __expf(-xr[k]));  // sigmoid
      c2[k] = mr[k] * bb;                         // mask*b
      c1[k] = mr[k] - c2[k];                      // mask*(1-b)
      w[k] = 1.0f - cs[k];
      fut[k] = fmaxf(mr[k] - cs[k], 0.0f);
      S += fut[k];
      wmn = fminf(wmn, w[k]);
    }

    // wave-level inclusive suffix-sum (for mfm) and suffix-min (for w>=0)
    float suf = S, wsc = wmn;
#pragma unroll
    for (int off = 1; off < 64; off <<= 1) {
      float t1 = __shfl_down(suf, (unsigned)off, 64);
      float t2 = __shfl_down(wsc, (unsigned)off, 64);
      bool ok = (lane + off) < 64;
      suf = ok ? (suf + t1) : suf;
      wsc = ok ? fminf(wsc, t2) : wsc;
    }
    // bit i set <=> min of w over columns [8i, 512) is >= 0
    const unsigned long long okm = __ballot(wsc >= 0.0f);

    const float R = suf - S;  // sum of fut over lanes > lane
    float mfm[8];
    float ls = 0.0f;
#pragma unroll
    for (int k = 7; k >= 0; --k) {  // mfm[k] = R + sum_{j>k local} fut[j]
      mfm[k] = R + ls;
      ls += fut[k];
    }
#pragma unroll
    for (int k = 0; k < 8; ++k) {
      int n = lane * 8 + k;
      cons[n + (n >> 3)] = make_float4(mfm[k], w[k], c1[k], c2[k]);
    }
    __syncthreads();

    int stop = NDIM;
    if (lane == 0) {
      float u = 1.0f;
      float4 cur[16];
#pragma unroll
      for (int k = 0; k < 16; ++k) cur[k] = cons[k + (k >> 3)];
#pragma unroll 1
      for (int c = 0; c < 32; ++c) {
        // exact-tail exit: all remaining p <= u < 1e-12 given w >= 0
        if (fabsf(u) < 1e-12f && ((okm >> (unsigned)(2 * c)) & 1ull)) {
          stop = c * 16;
          break;
        }
        float4 nxt[16];
        const int cn = (c < 31) ? (c + 1) : c;
#pragma unroll
        for (int k = 0; k < 16; ++k) {  // prefetch next chunk
          int n = cn * 16 + k;
          nxt[k] = cons[n + (n >> 3)];
        }
#pragma unroll
        for (int k = 0; k < 16; ++k) {  // 3-dependent-op chain per column
          float4 q = cur[k];
          float L = fmaxf(u - q.x, 0.0f);
          float U = fminf(u, q.y);
          float un = fmaf(-q.z, L, fmaf(-q.w, U, u));
          pbuf[c * 16 + k] = u - un;
          u = un;
        }
#pragma unroll
        for (int k = 0; k < 16; ++k) cur[k] = nxt[k];
      }
    }
    __syncthreads();
    stop = __shfl(stop, 0, 64);

    float4 p0 = *(const float4*)&pbuf[lane * 8];
    float4 p1 = *(const float4*)&pbuf[lane * 8 + 4];
    float pv[8] = {p0.x, p0.y, p0.z, p0.w, p1.x, p1.y, p1.z, p1.w};
#pragma unroll
    for (int k = 0; k < 8; ++k) {
      int n = lane * 8 + k;
      float p = (n < stop) ? pv[k] : 0.0f;
      cs[k] += p;
      pv[k] = p;
    }
    float* orow = ob + (size_t)m * NDIM;
    *(float4*)(orow + lane * 8) = make_float4(pv[0], pv[1], pv[2], pv[3]);
    *(float4*)(orow + lane * 8 + 4) = make_float4(pv[4], pv[5], pv[6], pv[7]);
    __syncthreads();
  }
}

extern "C" void kernel_launch(void* const* d_in, const int* in_sizes, int n_in,
                              void* d_out, int out_size, void* d_ws, size_t ws_size,
                              hipStream_t stream) {
  const float* x = (const float*)d_in[0];
  const float* xmask = (const float*)d_in[1];
  float* out = (float*)d_out;
  (void)in_sizes; (void)n_in; (void)out_size; (void)d_ws; (void)ws_size;
  hipLaunchKernelGGL(sb_kernel, dim3(NBATCH), dim3(64), 0, stream, x, xmask, out);
}